// Round 11
// baseline (429.004 us; speedup 1.0000x reference)
//
#include <hip/hip_runtime.h>

#define HC 128          // H*C = output dim
#define HEADS 8
#define CPH 16
#define EDIM 16
#define NG 8
#define GEPS 1e-5f
#define LOG2E 1.44269504f

typedef float f32x2 __attribute__((ext_vector_type(2)));

// ---------- bf16x2 pack/unpack (round-to-nearest-even) ----------
__device__ __forceinline__ unsigned pack_bf16x2(float a, float b) {
  unsigned ua = __float_as_uint(a), ub = __float_as_uint(b);
  ua = (ua + 0x7fffu + ((ua >> 16) & 1u)) >> 16;
  ub = (ub + 0x7fffu + ((ub >> 16) & 1u)) >> 16;
  return ua | (ub << 16);
}
__device__ __forceinline__ f32x2 unpack_bf16x2(unsigned u) {
  return (f32x2){__uint_as_float(u << 16), __uint_as_float(u & 0xffff0000u)};
}

// ---------- 8-lane (head) sum via DPP: half_mirror + quad_perm xor2/xor1 ----------
__device__ __forceinline__ float head8_sum(float p) {
  int t;
  t = __builtin_amdgcn_update_dpp(0, __float_as_int(p), 0x141, 0xF, 0xF, true); // row_half_mirror
  p += __int_as_float(t);
  t = __builtin_amdgcn_update_dpp(0, __float_as_int(p), 0x4E, 0xF, 0xF, true);  // quad_perm [2,3,0,1]
  p += __int_as_float(t);
  t = __builtin_amdgcn_update_dpp(0, __float_as_int(p), 0xB1, 0xF, 0xF, true);  // quad_perm [1,0,3,2]
  p += __int_as_float(t);
  return p;
}

// ---------- K0: zero scratch ----------
__global__ void zero_k(float* __restrict__ p, size_t nwords) {
  size_t i = (size_t)blockIdx.x * 256 + threadIdx.x;
  if (i < nwords) p[i] = 0.f;
}

// ---------- K1: degree of real edges (by dst) + group-boundary marks ----------
__global__ void count_deg_mark(const int* __restrict__ ei, int* __restrict__ deg,
                               const int* __restrict__ batch, int* __restrict__ genc,
                               int E, int N) {
  int e = blockIdx.x * 256 + threadIdx.x;
  if (e >= E) return;
  atomicAdd(&deg[ei[E + e]], 1);
  if (e < N && (e == 0 || batch[e] != batch[e - 1])) {
    // encode start index i as (N - i) so zero-init means "empty group"
    atomicMax(&genc[batch[e]], N - e);
  }
}

// ---------- K2: xl = x@Wl+bl (fp32 + bf16 copy), xr = x@Wr+br ----------
#define GEMM_ROWS 32
__global__ void __launch_bounds__(256) gemm_tiled(
    const float* __restrict__ x,
    const float* __restrict__ Wl, const float* __restrict__ bl,
    const float* __restrict__ Wr, const float* __restrict__ br,
    float* __restrict__ xl, float* __restrict__ xr,
    unsigned* __restrict__ xlh, int N) {
  __shared__ float4 WL[32][32];   // [k within chunk][col float4 group] 16KB
  __shared__ float4 WR[32][32];   // 16KB
  __shared__ float4 XS[GEMM_ROWS][8];  // [local row][k4 within chunk] 4KB
  int t = threadIdx.x;
  int cg = t & 31;                // col float4 group (0..31)
  int rt = t >> 5;                // row-thread (0..7), owns rows rt*4..rt*4+3
  int row0 = blockIdx.x * GEMM_ROWS;
  float4 bl4 = ((const float4*)bl)[cg];
  float4 br4 = ((const float4*)br)[cg];
  float4 accl[4], accr[4];
  #pragma unroll
  for (int r = 0; r < 4; ++r) { accl[r] = bl4; accr[r] = br4; }
  const float4* Wl4 = (const float4*)Wl;
  const float4* Wr4 = (const float4*)Wr;
  const float4* x4  = (const float4*)x;
  int srow = t >> 3, sk4 = t & 7;
  long sgrow = row0 + srow;
  for (int kc = 0; kc < 4; ++kc) {
    __syncthreads();              // previous chunk fully consumed
    #pragma unroll
    for (int i = 0; i < 4; ++i) {
      int idx = t + i * 256;      // 0..1023
      int kr = idx >> 5, gg = idx & 31;
      WL[kr][gg] = Wl4[(kc * 32 + kr) * 32 + gg];
      WR[kr][gg] = Wr4[(kc * 32 + kr) * 32 + gg];
    }
    XS[srow][sk4] = (sgrow < N) ? x4[sgrow * 32 + kc * 8 + sk4]
                                : make_float4(0.f, 0.f, 0.f, 0.f);
    __syncthreads();
    #pragma unroll
    for (int k4 = 0; k4 < 8; ++k4) {
      float4 xv[4];
      #pragma unroll
      for (int r = 0; r < 4; ++r) xv[r] = XS[rt * 4 + r][k4];
      #pragma unroll
      for (int kk = 0; kk < 4; ++kk) {
        float4 wl = WL[k4 * 4 + kk][cg];
        float4 wr = WR[k4 * 4 + kk][cg];
        #pragma unroll
        for (int r = 0; r < 4; ++r) {
          float xs = (&xv[r].x)[kk];
          accl[r].x = fmaf(xs, wl.x, accl[r].x);
          accl[r].y = fmaf(xs, wl.y, accl[r].y);
          accl[r].z = fmaf(xs, wl.z, accl[r].z);
          accl[r].w = fmaf(xs, wl.w, accl[r].w);
          accr[r].x = fmaf(xs, wr.x, accr[r].x);
          accr[r].y = fmaf(xs, wr.y, accr[r].y);
          accr[r].z = fmaf(xs, wr.z, accr[r].z);
          accr[r].w = fmaf(xs, wr.w, accr[r].w);
        }
      }
    }
  }
  #pragma unroll
  for (int r = 0; r < 4; ++r) {
    long row = row0 + rt * 4 + r;
    if (row < N) {
      ((float4*)(xl + row * HC))[cg] = accl[r];
      ((float4*)(xr + row * HC))[cg] = accr[r];
      uint2 h;
      h.x = pack_bf16x2(accl[r].x, accl[r].y);
      h.y = pack_bf16x2(accl[r].z, accl[r].w);
      ((uint2*)(xlh + row * (HC / 2)))[cg] = h;
    }
  }
}

// ---------- K3: scan of deg -> offsets (CSR) ----------
__global__ void scan1(const int* __restrict__ deg, int* __restrict__ bsum, int N) {
  __shared__ int s[256];
  int t = threadIdx.x;
  int n = blockIdx.x * 256 + t;
  s[t] = (n < N) ? deg[n] : 0;
  __syncthreads();
  for (int off = 128; off > 0; off >>= 1) {
    if (t < off) s[t] += s[t + off];
    __syncthreads();
  }
  if (t == 0) bsum[blockIdx.x] = s[0];
}
// parallel scan of block sums (nb <= 256) + group-start decode; 1 block x 256
__global__ void scan2(const int* __restrict__ bsum, int* __restrict__ bofs, int nb,
                      int* __restrict__ offsets, int N,
                      const int* __restrict__ genc, int* __restrict__ gstart) {
  __shared__ int s[256];
  int t = threadIdx.x;
  int v = (t < nb) ? bsum[t] : 0;
  s[t] = v;
  __syncthreads();
  for (int off = 1; off < 256; off <<= 1) {
    int add = (t >= off) ? s[t - off] : 0;
    __syncthreads();
    s[t] += add;
    __syncthreads();
  }
  if (t < nb) bofs[t] = s[t] - v;        // exclusive
  if (t == 255) offsets[N] = s[255];     // total (tail lanes contribute 0)
  if (t == 0) {
    // decode group starts; suffix-min so empty groups collapse to 0-length
    int nxt = N;
    gstart[NG] = N;
    for (int g = NG - 1; g >= 0; --g) {
      int st = N - genc[g];
      if (st > nxt) st = nxt;
      gstart[g] = st;
      nxt = st;
    }
  }
}
__global__ void scan3(const int* __restrict__ deg, const int* __restrict__ bofs,
                      int* __restrict__ offsets, int N) {
  __shared__ int s[256];
  int t = threadIdx.x;
  int n = blockIdx.x * 256 + t;
  int v = (n < N) ? deg[n] : 0;
  s[t] = v;
  __syncthreads();
  for (int off = 1; off < 256; off <<= 1) {
    int add = (t >= off) ? s[t - off] : 0;
    __syncthreads();
    s[t] += add;
    __syncthreads();
  }
  if (n < N) offsets[n] = bofs[blockIdx.x] + s[t] - v;  // exclusive
}

// ---------- K4: fill CSR with (edge, src) pairs; consumes deg ----------
__global__ void fill_csr(const int* __restrict__ ei, int* __restrict__ deg,
                         const int* __restrict__ offsets, int2* __restrict__ csr2, int E) {
  int e = blockIdx.x * 256 + threadIdx.x;
  if (e >= E) return;
  int d = ei[E + e];
  int pos = atomicSub(&deg[d], 1) - 1;
  csr2[offsets[d] + pos] = make_int2(e, ei[e]);
}

// ---------- K5: FUSED attention + defer-max online softmax + aggregation ----------
// 256 thr = 4 waves = 2 NODES; each node's edge list is SPLIT across 2 waves
// (R10 post-mortem: kernel is bound by serial-chain-length x chain-count;
// R7's 1 wave/node halved chain count vs R6 -- this restores it at f32x2 cost).
// Each wave runs its own online-softmax state over half the edges; states are
// merged via LDS: M=max(m0,m1), den=den0*2^(m0-M)+den1*2^(m1-M), acc likewise,
// eesum adds linearly. Lane l owns channels (2l,2l+1) packed f32x2; neighbor
// xl gathered in bf16 (xlh). Self-loop (ea fill 'mean') merged via linearity.
__global__ void __launch_bounds__(256) fused_node(
    const int* __restrict__ offsets, const int2* __restrict__ csr2,
    const float* __restrict__ ea, const unsigned* __restrict__ xlh,
    const float* __restrict__ xl, const float* __restrict__ xr,
    const float* __restrict__ We, const float* __restrict__ att,
    const float* __restrict__ x, const float* __restrict__ bias,
    float* __restrict__ out, int N) {
  __shared__ float sm[2][8], sd[2][8];       // wave-1 partial m, den per head
  __shared__ f32x2 sacc[2][64], see[2][64];  // wave-1 partial acc, eesum per lane
  int t = threadIdx.x;
  int l = t & 63;
  int half = (t >> 6) & 1;
  int slot = t >> 7;                         // node slot within block (0/1)
  long n = (long)blockIdx.x * 2 + slot;
  bool active = (n < N);
  long nc = active ? n : 0;                  // clamped for safe loads
  int c0 = l * 2;
  f32x2 wx[8], wy[8];
  #pragma unroll
  for (int kp = 0; kp < 8; ++kp) {
    wx[kp] = (f32x2){We[(2 * kp) * HC + c0],     We[(2 * kp + 1) * HC + c0]};
    wy[kp] = (f32x2){We[(2 * kp) * HC + c0 + 1], We[(2 * kp + 1) * HC + c0 + 1]};
  }
  f32x2 av2 = {att[c0] * LOG2E, att[c0 + 1] * LOG2E};
  f32x2 av08 = 0.8f * av2, av02 = 0.2f * av2;
  f32x2 xl2 = *(const f32x2*)(xl + nc * HC + c0);
  f32x2 xr2 = *(const f32x2*)(xr + nc * HC + c0);
  f32x2 seedA = {xr2.x, 0.f};   // dot-accumulator seeds (fold +xr into hadd)
  f32x2 seedB = {xr2.y, 0.f};
  int j0 = 0, j1 = 0;
  if (active) { j0 = offsets[n]; j1 = offsets[n + 1]; }
  int jm = j0 + ((j1 - j0 + 1) >> 1);
  int a = half ? jm : j0;
  int b = half ? j1 : jm;

  float m = -INFINITY;          // running max (log2), uniform per 8-lane head
  float den = 0.f;
  f32x2 acc = {0.f, 0.f};
  f32x2 eesum = {0.f, 0.f};     // per-channel sum of (eev + xr)

  auto edge_update = [&](int e, f32x2 xls) {
    const float4* eap = (const float4*)(ea + (long)e * EDIM);
    float4 a0 = eap[0], a1 = eap[1], a2 = eap[2], a3 = eap[3];
    f32x2 dA = seedA, dB = seedB;
    f32x2 e01;
    e01 = (f32x2){a0.x, a0.y};
    dA = __builtin_elementwise_fma(e01, wx[0], dA);
    dB = __builtin_elementwise_fma(e01, wy[0], dB);
    e01 = (f32x2){a0.z, a0.w};
    dA = __builtin_elementwise_fma(e01, wx[1], dA);
    dB = __builtin_elementwise_fma(e01, wy[1], dB);
    e01 = (f32x2){a1.x, a1.y};
    dA = __builtin_elementwise_fma(e01, wx[2], dA);
    dB = __builtin_elementwise_fma(e01, wy[2], dB);
    e01 = (f32x2){a1.z, a1.w};
    dA = __builtin_elementwise_fma(e01, wx[3], dA);
    dB = __builtin_elementwise_fma(e01, wy[3], dB);
    e01 = (f32x2){a2.x, a2.y};
    dA = __builtin_elementwise_fma(e01, wx[4], dA);
    dB = __builtin_elementwise_fma(e01, wy[4], dB);
    e01 = (f32x2){a2.z, a2.w};
    dA = __builtin_elementwise_fma(e01, wx[5], dA);
    dB = __builtin_elementwise_fma(e01, wy[5], dB);
    e01 = (f32x2){a3.x, a3.y};
    dA = __builtin_elementwise_fma(e01, wx[6], dA);
    dB = __builtin_elementwise_fma(e01, wy[6], dB);
    e01 = (f32x2){a3.z, a3.w};
    dA = __builtin_elementwise_fma(e01, wx[7], dA);
    dB = __builtin_elementwise_fma(e01, wy[7], dB);
    f32x2 mm = {dA.x + dA.y, dB.x + dB.y};   // = eev + xr (per channel)
    eesum += mm;
    mm += xls;
    f32x2 tt = __builtin_elementwise_fma(
        av08, __builtin_elementwise_max(mm, (f32x2)0.f), av02 * mm);
    float p = head8_sum(tt.x + tt.y);  // head logit, uniform in 8-lane group
    if (p > m + 11.5f) {               // rare: new max grew past threshold
      float sc = exp2f(m - p);
      acc = acc * sc + xls;
      den = fmaf(den, sc, 1.f);
      m = p;
    } else {                           // common: single exp2, no rescale
      float w = exp2f(p - m);
      acc = __builtin_elementwise_fma((f32x2)w, xls, acc);
      den += w;
    }
  };

  auto gath = [&](int s) -> f32x2 {
    return unpack_bf16x2(xlh[(long)s * (HC / 2) + l]);   // 4B/lane bf16 gather
  };
  auto edge_single = [&](int jj) {
    int2 es = csr2[jj];
    int e = __builtin_amdgcn_readfirstlane(es.x);
    int s = __builtin_amdgcn_readfirstlane(es.y);
    edge_update(e, gath(s));
  };

  int j = a;
  if ((j & 1) && j < b) { edge_single(j); ++j; }   // peel to 16B alignment
  for (; j + 1 < b; j += 2) {
    int4 q = *(const int4*)(csr2 + j);  // two (edge,src) pairs, one dwordx4
    int e0 = __builtin_amdgcn_readfirstlane(q.x);
    int s0 = __builtin_amdgcn_readfirstlane(q.y);
    int e1 = __builtin_amdgcn_readfirstlane(q.z);
    int s1 = __builtin_amdgcn_readfirstlane(q.w);
    f32x2 xls0 = gath(s0);
    f32x2 xls1 = gath(s1);
    edge_update(e0, xls0);
    edge_update(e1, xls1);
  }
  if (j < b) edge_single(j);

  // ---- publish wave-1 partials, then wave-0 merges ----
  if (half) {
    if ((l & 7) == 0) { sm[slot][l >> 3] = m; sd[slot][l >> 3] = den; }
    sacc[slot][l] = acc;
    see[slot][l] = eesum;
  }
  __syncthreads();
  if (half || !active) return;

  {
    float m1 = sm[slot][l >> 3];
    float d1 = sd[slot][l >> 3];
    f32x2 a1 = sacc[slot][l];
    f32x2 e1 = see[slot][l];
    float M = fmaxf(m, m1);
    if (M != -INFINITY) {
      float s0 = exp2f(m - M);
      float s1 = exp2f(m1 - M);
      acc = acc * s0 + a1 * s1;
      den = den * s0 + d1 * s1;
      m = M;
    }
    eesum += e1;
  }

  // ---- self-loop ----
  int dg = j1 - j0;
  f32x2 ee = (dg > 0) ? (eesum * (1.f / (float)dg) - xr2) : (f32x2)0.f;
  f32x2 mm = xl2 + xr2 + ee;
  f32x2 tt = __builtin_elementwise_fma(
      av08, __builtin_elementwise_max(mm, (f32x2)0.f), av02 * mm);
  float p = head8_sum(tt.x + tt.y);
  if (p > m) {
    float sc = exp2f(m - p);
    acc = acc * sc + xl2;
    den = fmaf(den, sc, 1.f);
  } else {
    float w = exp2f(p - m);
    acc = __builtin_elementwise_fma((f32x2)w, xl2, acc);
    den += w;
  }

  f32x2 b2 = *(const f32x2*)(bias + c0);
  f32x2 x2 = *(const f32x2*)(x + n * HC + c0);
  f32x2 o = acc * (1.f / den) + b2 + x2;
  *(f32x2*)(out + n * HC + c0) = o;
}

// ---------- K6: GraphNorm segment sums (grid-parallel over group slices) ----------
#define GN_SLICES 32
__global__ void __launch_bounds__(128) gn_stats(
    const float* __restrict__ out, const int* __restrict__ gstart,
    float* __restrict__ gsum, float* __restrict__ gsq) {
  int g = blockIdx.x >> 5;
  int slice = blockIdx.x & 31;
  int s0 = gstart[g], s1 = gstart[g + 1];
  int cnt = s1 - s0;
  if (cnt <= 0) return;
  int chunk = (cnt + GN_SLICES - 1) / GN_SLICES;
  int lo = s0 + slice * chunk;
  int hi = lo + chunk; if (hi > s1) hi = s1;
  if (lo >= hi) return;
  int ch = threadIdx.x;
  float sum = 0.f, sq = 0.f;
  for (int nrow = lo; nrow < hi; ++nrow) {
    float v = out[(long)nrow * HC + ch];
    sum += v; sq += v * v;
  }
  atomicAdd(&gsum[g * HC + ch], sum);
  atomicAdd(&gsq[g * HC + ch], sq);
}

// ---------- K7: normalize + affine + ELU, with inline mean/istd (fused finalize) ----
__global__ void gn_apply(float* __restrict__ out, const int* __restrict__ batch,
                         const float* __restrict__ gsum, const float* __restrict__ gsq,
                         const int* __restrict__ gstart, const float* __restrict__ gms,
                         const float* __restrict__ gnw, const float* __restrict__ gnb, int N) {
  long i = (long)blockIdx.x * 256 + threadIdx.x;     // float4 index
  if (i >= (long)N * 32) return;
  int c4 = (int)(i & 31);
  long n = i >> 5;
  int g = batch[n];
  float cnt = (float)(gstart[g + 1] - gstart[g]);
  if (cnt < 1.f) cnt = 1.f;
  float ic = 1.f / cnt;
  float4 su = ((const float4*)gsum)[g * 32 + c4];
  float4 sq = ((const float4*)gsq)[g * 32 + c4];
  float4 ms4 = ((const float4*)gms)[c4];
  float4 v = ((const float4*)out)[i];
  float4 w  = ((const float4*)gnw)[c4];
  float4 b  = ((const float4*)gnb)[c4];
  float4 o;
  #pragma unroll
  for (int k = 0; k < 4; ++k) {
    float mean = (&su.x)[k] * ic;
    float c = (&ms4.x)[k] * mean;                       // subtracted constant
    float var = (&sq.x)[k] * ic - 2.f * c * mean + c * c;
    float istd = rsqrtf(var + GEPS);
    float oo = fmaf((&w.x)[k] * ((&v.x)[k] - c), istd, (&b.x)[k]);
    (&o.x)[k] = oo > 0.f ? oo : expm1f(oo);
  }
  ((float4*)out)[i] = o;
}

extern "C" void kernel_launch(void* const* d_in, const int* in_sizes, int n_in,
                              void* d_out, int out_size, void* d_ws, size_t ws_size,
                              hipStream_t stream) {
  const float* x    = (const float*)d_in[0];
  const int*   ei   = (const int*)d_in[1];
  const float* ea   = (const float*)d_in[2];
  const int*   batch= (const int*)d_in[3];
  const float* Wl   = (const float*)d_in[4];
  const float* bl   = (const float*)d_in[5];
  const float* Wr   = (const float*)d_in[6];
  const float* br   = (const float*)d_in[7];
  const float* We   = (const float*)d_in[8];
  const float* att  = (const float*)d_in[9];
  const float* bias = (const float*)d_in[10];
  const float* gnw  = (const float*)d_in[11];
  const float* gnb  = (const float*)d_in[12];
  const float* gms  = (const float*)d_in[13];
  int N = in_sizes[0] / HC;
  int E = in_sizes[2] / EDIM;
  float* out = (float*)d_out;
  (void)n_in; (void)out_size; (void)ws_size;

  // ---- workspace carve-up (4-byte words, 16B aligned blocks) ----
  float* wsf = (float*)d_ws;
  size_t off = 0;
  auto alloc = [&](size_t words) -> float* {
    float* p = wsf + off;
    off += (words + 3) & ~(size_t)3;
    return p;
  };
  int*      deg     = (int*)alloc(N);
  float*    gsum    = alloc(NG * HC);
  float*    gsq     = alloc(NG * HC);
  int*      genc    = (int*)alloc(NG);
  size_t zero_words = off;                 // everything above starts at 0
  int*      gstart  = (int*)alloc(NG + 1);
  int*      bsum    = (int*)alloc(256);
  int*      bofs    = (int*)alloc(256);
  int*      offsets = (int*)alloc((size_t)N + 1);
  float*    xl      = alloc((size_t)N * HC);
  float*    xr      = alloc((size_t)N * HC);
  unsigned* xlh     = (unsigned*)alloc((size_t)N * (HC / 2));
  int2*     csr2    = (int2*)alloc((size_t)E * 2 + 8);

  int nb = (N + 255) / 256;   // scan blocks (<=256 by construction for N<=65536)

  zero_k<<<(unsigned)((zero_words + 255) / 256), 256, 0, stream>>>(wsf, zero_words);
  count_deg_mark<<<(E + 255) / 256, 256, 0, stream>>>(ei, deg, batch, genc, E, N);
  gemm_tiled<<<(N + GEMM_ROWS - 1) / GEMM_ROWS, 256, 0, stream>>>(x, Wl, bl, Wr, br, xl, xr, xlh, N);
  scan1<<<nb, 256, 0, stream>>>(deg, bsum, N);
  scan2<<<1, 256, 0, stream>>>(bsum, bofs, nb, offsets, N, genc, gstart);
  scan3<<<nb, 256, 0, stream>>>(deg, bofs, offsets, N);
  fill_csr<<<(E + 255) / 256, 256, 0, stream>>>(ei, deg, offsets, csr2, E);
  fused_node<<<(N + 1) / 2, 256, 0, stream>>>(offsets, csr2, ea, xlh, xl, xr, We, att, x, bias, out, N);
  gn_stats<<<NG * GN_SLICES, 128, 0, stream>>>(out, gstart, gsum, gsq);
  {
    long tot = (long)N * 32;
    gn_apply<<<(unsigned)((tot + 255) / 256), 256, 0, stream>>>(out, batch, gsum, gsq, gstart, gms, gnw, gnb, N);
  }
}

// Round 12
// 348.751 us; speedup vs baseline: 1.2301x; 1.2301x over previous
//
#include <hip/hip_runtime.h>

#define HC 128          // H*C = output dim
#define HEADS 8
#define CPH 16
#define EDIM 16
#define NG 8
#define GEPS 1e-5f
#define LOG2E 1.44269504f

typedef float f32x2 __attribute__((ext_vector_type(2)));

// ---------- bf16x2 pack/unpack (round-to-nearest-even) ----------
__device__ __forceinline__ unsigned pack_bf16x2(float a, float b) {
  unsigned ua = __float_as_uint(a), ub = __float_as_uint(b);
  ua = (ua + 0x7fffu + ((ua >> 16) & 1u)) >> 16;
  ub = (ub + 0x7fffu + ((ub >> 16) & 1u)) >> 16;
  return ua | (ub << 16);
}
__device__ __forceinline__ f32x2 unpack_bf16x2(unsigned u) {
  return (f32x2){__uint_as_float(u << 16), __uint_as_float(u & 0xffff0000u)};
}

// ---------- 8-lane (head) sum via DPP: half_mirror + quad_perm xor2/xor1 ----------
__device__ __forceinline__ float head8_sum(float p) {
  int t;
  t = __builtin_amdgcn_update_dpp(0, __float_as_int(p), 0x141, 0xF, 0xF, true); // row_half_mirror
  p += __int_as_float(t);
  t = __builtin_amdgcn_update_dpp(0, __float_as_int(p), 0x4E, 0xF, 0xF, true);  // quad_perm [2,3,0,1]
  p += __int_as_float(t);
  t = __builtin_amdgcn_update_dpp(0, __float_as_int(p), 0xB1, 0xF, 0xF, true);  // quad_perm [1,0,3,2]
  p += __int_as_float(t);
  return p;
}

// ---------- K0: zero scratch ----------
__global__ void zero_k(float* __restrict__ p, size_t nwords) {
  size_t i = (size_t)blockIdx.x * 256 + threadIdx.x;
  if (i < nwords) p[i] = 0.f;
}

// ---------- K1: degree of real edges (by dst) + group-boundary marks ----------
__global__ void count_deg_mark(const int* __restrict__ ei, int* __restrict__ deg,
                               const int* __restrict__ batch, int* __restrict__ genc,
                               int E, int N) {
  int e = blockIdx.x * 256 + threadIdx.x;
  if (e >= E) return;
  atomicAdd(&deg[ei[E + e]], 1);
  if (e < N && (e == 0 || batch[e] != batch[e - 1])) {
    // encode start index i as (N - i) so zero-init means "empty group"
    atomicMax(&genc[batch[e]], N - e);
  }
}

// ---------- K2: xl = x@Wl+bl (fp32 + bf16 copy), xr = x@Wr+br ----------
#define GEMM_ROWS 32
__global__ void __launch_bounds__(256) gemm_tiled(
    const float* __restrict__ x,
    const float* __restrict__ Wl, const float* __restrict__ bl,
    const float* __restrict__ Wr, const float* __restrict__ br,
    float* __restrict__ xl, float* __restrict__ xr,
    unsigned* __restrict__ xlh, int N) {
  __shared__ float4 WL[32][32];   // [k within chunk][col float4 group] 16KB
  __shared__ float4 WR[32][32];   // 16KB
  __shared__ float4 XS[GEMM_ROWS][8];  // [local row][k4 within chunk] 4KB
  int t = threadIdx.x;
  int cg = t & 31;                // col float4 group (0..31)
  int rt = t >> 5;                // row-thread (0..7), owns rows rt*4..rt*4+3
  int row0 = blockIdx.x * GEMM_ROWS;
  float4 bl4 = ((const float4*)bl)[cg];
  float4 br4 = ((const float4*)br)[cg];
  float4 accl[4], accr[4];
  #pragma unroll
  for (int r = 0; r < 4; ++r) { accl[r] = bl4; accr[r] = br4; }
  const float4* Wl4 = (const float4*)Wl;
  const float4* Wr4 = (const float4*)Wr;
  const float4* x4  = (const float4*)x;
  int srow = t >> 3, sk4 = t & 7;
  long sgrow = row0 + srow;
  for (int kc = 0; kc < 4; ++kc) {
    __syncthreads();              // previous chunk fully consumed
    #pragma unroll
    for (int i = 0; i < 4; ++i) {
      int idx = t + i * 256;      // 0..1023
      int kr = idx >> 5, gg = idx & 31;
      WL[kr][gg] = Wl4[(kc * 32 + kr) * 32 + gg];
      WR[kr][gg] = Wr4[(kc * 32 + kr) * 32 + gg];
    }
    XS[srow][sk4] = (sgrow < N) ? x4[sgrow * 32 + kc * 8 + sk4]
                                : make_float4(0.f, 0.f, 0.f, 0.f);
    __syncthreads();
    #pragma unroll
    for (int k4 = 0; k4 < 8; ++k4) {
      float4 xv[4];
      #pragma unroll
      for (int r = 0; r < 4; ++r) xv[r] = XS[rt * 4 + r][k4];
      #pragma unroll
      for (int kk = 0; kk < 4; ++kk) {
        float4 wl = WL[k4 * 4 + kk][cg];
        float4 wr = WR[k4 * 4 + kk][cg];
        #pragma unroll
        for (int r = 0; r < 4; ++r) {
          float xs = (&xv[r].x)[kk];
          accl[r].x = fmaf(xs, wl.x, accl[r].x);
          accl[r].y = fmaf(xs, wl.y, accl[r].y);
          accl[r].z = fmaf(xs, wl.z, accl[r].z);
          accl[r].w = fmaf(xs, wl.w, accl[r].w);
          accr[r].x = fmaf(xs, wr.x, accr[r].x);
          accr[r].y = fmaf(xs, wr.y, accr[r].y);
          accr[r].z = fmaf(xs, wr.z, accr[r].z);
          accr[r].w = fmaf(xs, wr.w, accr[r].w);
        }
      }
    }
  }
  #pragma unroll
  for (int r = 0; r < 4; ++r) {
    long row = row0 + rt * 4 + r;
    if (row < N) {
      ((float4*)(xl + row * HC))[cg] = accl[r];
      ((float4*)(xr + row * HC))[cg] = accr[r];
      uint2 h;
      h.x = pack_bf16x2(accl[r].x, accl[r].y);
      h.y = pack_bf16x2(accl[r].z, accl[r].w);
      ((uint2*)(xlh + row * (HC / 2)))[cg] = h;
    }
  }
}

// ---------- K3: scan of deg -> offsets (CSR) ----------
__global__ void scan1(const int* __restrict__ deg, int* __restrict__ bsum, int N) {
  __shared__ int s[256];
  int t = threadIdx.x;
  int n = blockIdx.x * 256 + t;
  s[t] = (n < N) ? deg[n] : 0;
  __syncthreads();
  for (int off = 128; off > 0; off >>= 1) {
    if (t < off) s[t] += s[t + off];
    __syncthreads();
  }
  if (t == 0) bsum[blockIdx.x] = s[0];
}
// parallel scan of block sums (nb <= 256) + group-start decode; 1 block x 256
__global__ void scan2(const int* __restrict__ bsum, int* __restrict__ bofs, int nb,
                      int* __restrict__ offsets, int N,
                      const int* __restrict__ genc, int* __restrict__ gstart) {
  __shared__ int s[256];
  int t = threadIdx.x;
  int v = (t < nb) ? bsum[t] : 0;
  s[t] = v;
  __syncthreads();
  for (int off = 1; off < 256; off <<= 1) {
    int add = (t >= off) ? s[t - off] : 0;
    __syncthreads();
    s[t] += add;
    __syncthreads();
  }
  if (t < nb) bofs[t] = s[t] - v;        // exclusive
  if (t == 255) offsets[N] = s[255];     // total (tail lanes contribute 0)
  if (t == 0) {
    // decode group starts; suffix-min so empty groups collapse to 0-length
    int nxt = N;
    gstart[NG] = N;
    for (int g = NG - 1; g >= 0; --g) {
      int st = N - genc[g];
      if (st > nxt) st = nxt;
      gstart[g] = st;
      nxt = st;
    }
  }
}
__global__ void scan3(const int* __restrict__ deg, const int* __restrict__ bofs,
                      int* __restrict__ offsets, int N) {
  __shared__ int s[256];
  int t = threadIdx.x;
  int n = blockIdx.x * 256 + t;
  int v = (n < N) ? deg[n] : 0;
  s[t] = v;
  __syncthreads();
  for (int off = 1; off < 256; off <<= 1) {
    int add = (t >= off) ? s[t - off] : 0;
    __syncthreads();
    s[t] += add;
    __syncthreads();
  }
  if (n < N) offsets[n] = bofs[blockIdx.x] + s[t] - v;  // exclusive
}

// ---------- K4: fill CSR with (edge, src) pairs; consumes deg ----------
__global__ void fill_csr(const int* __restrict__ ei, int* __restrict__ deg,
                         const int* __restrict__ offsets, int2* __restrict__ csr2, int E) {
  int e = blockIdx.x * 256 + threadIdx.x;
  if (e >= E) return;
  int d = ei[E + e];
  int pos = atomicSub(&deg[d], 1) - 1;
  csr2[offsets[d] + pos] = make_int2(e, ei[e]);
}

// ---------- K5: FUSED per-node attention + defer-max online softmax + agg ----------
// ONE WAVE per node, ONE 64-thread BLOCK per wave (R11 post-mortem: packing 4
// independent nodes into a 256-thr block couples their lifetimes -- the block
// retires on its SLOWEST wave, wasting ~30% of wave-slots with Poisson degrees;
// R6's 1-node blocks hit 84-90% occupancy vs 46-54% for R7-R11).
// Lane l owns channels (2l,2l+1) packed f32x2 (v_pk_fma). Neighbor xl gathered
// in bf16 (4B/lane). Head = 8 lanes -> 3-stage DPP. Self-loop (ea fill 'mean')
// merged via linearity. Logits in log2 space (att pre-scaled by log2e).
__global__ void __launch_bounds__(64) fused_node(
    const int* __restrict__ offsets, const int2* __restrict__ csr2,
    const float* __restrict__ ea, const unsigned* __restrict__ xlh,
    const float* __restrict__ xl, const float* __restrict__ xr,
    const float* __restrict__ We, const float* __restrict__ att,
    const float* __restrict__ x, const float* __restrict__ bias,
    float* __restrict__ out, int N) {
  int l = threadIdx.x;
  long n = blockIdx.x;
  if (n >= N) return;
  int c0 = l * 2;
  // We pairs, k-major: wx[kp] = (We[2kp][c0], We[2kp+1][c0]); wy for c0+1.
  f32x2 wx[8], wy[8];
  #pragma unroll
  for (int kp = 0; kp < 8; ++kp) {
    wx[kp] = (f32x2){We[(2 * kp) * HC + c0],     We[(2 * kp + 1) * HC + c0]};
    wy[kp] = (f32x2){We[(2 * kp) * HC + c0 + 1], We[(2 * kp + 1) * HC + c0 + 1]};
  }
  f32x2 av2 = {att[c0] * LOG2E, att[c0 + 1] * LOG2E};
  f32x2 av08 = 0.8f * av2, av02 = 0.2f * av2;
  f32x2 xl2 = *(const f32x2*)(xl + n * HC + c0);
  f32x2 xr2 = *(const f32x2*)(xr + n * HC + c0);
  f32x2 seedA = {xr2.x, 0.f};   // dot-accumulator seeds (fold +xr into hadd)
  f32x2 seedB = {xr2.y, 0.f};
  int j0 = offsets[n], j1 = offsets[n + 1];

  float m = -INFINITY;          // running max (log2), uniform per 8-lane head
  float den = 0.f;
  f32x2 acc = {0.f, 0.f};
  f32x2 eesum = {0.f, 0.f};     // per-channel sum of (eev + xr); adjusted at end

  auto edge_update = [&](int e, f32x2 xls) {
    const float4* eap = (const float4*)(ea + (long)e * EDIM);
    float4 a0 = eap[0], a1 = eap[1], a2 = eap[2], a3 = eap[3];
    f32x2 dA = seedA, dB = seedB;
    f32x2 e01;
    e01 = (f32x2){a0.x, a0.y};
    dA = __builtin_elementwise_fma(e01, wx[0], dA);
    dB = __builtin_elementwise_fma(e01, wy[0], dB);
    e01 = (f32x2){a0.z, a0.w};
    dA = __builtin_elementwise_fma(e01, wx[1], dA);
    dB = __builtin_elementwise_fma(e01, wy[1], dB);
    e01 = (f32x2){a1.x, a1.y};
    dA = __builtin_elementwise_fma(e01, wx[2], dA);
    dB = __builtin_elementwise_fma(e01, wy[2], dB);
    e01 = (f32x2){a1.z, a1.w};
    dA = __builtin_elementwise_fma(e01, wx[3], dA);
    dB = __builtin_elementwise_fma(e01, wy[3], dB);
    e01 = (f32x2){a2.x, a2.y};
    dA = __builtin_elementwise_fma(e01, wx[4], dA);
    dB = __builtin_elementwise_fma(e01, wy[4], dB);
    e01 = (f32x2){a2.z, a2.w};
    dA = __builtin_elementwise_fma(e01, wx[5], dA);
    dB = __builtin_elementwise_fma(e01, wy[5], dB);
    e01 = (f32x2){a3.x, a3.y};
    dA = __builtin_elementwise_fma(e01, wx[6], dA);
    dB = __builtin_elementwise_fma(e01, wy[6], dB);
    e01 = (f32x2){a3.z, a3.w};
    dA = __builtin_elementwise_fma(e01, wx[7], dA);
    dB = __builtin_elementwise_fma(e01, wy[7], dB);
    f32x2 mm = {dA.x + dA.y, dB.x + dB.y};   // = eev + xr (per channel)
    eesum += mm;
    mm += xls;
    f32x2 tt = __builtin_elementwise_fma(
        av08, __builtin_elementwise_max(mm, (f32x2)0.f), av02 * mm);
    float p = head8_sum(tt.x + tt.y);  // head logit, uniform in 8-lane group
    if (p > m + 11.5f) {               // rare: new max grew past threshold
      float sc = exp2f(m - p);
      acc = acc * sc + xls;
      den = fmaf(den, sc, 1.f);
      m = p;
    } else {                           // common: single exp2, no rescale
      float w = exp2f(p - m);
      acc = __builtin_elementwise_fma((f32x2)w, xls, acc);
      den += w;
    }
  };

  auto gath = [&](int s) -> f32x2 {
    return unpack_bf16x2(xlh[(long)s * (HC / 2) + l]);   // 4B/lane bf16 gather
  };
  auto edge_single = [&](int jj) {
    int2 es = csr2[jj];
    int e = __builtin_amdgcn_readfirstlane(es.x);
    int s = __builtin_amdgcn_readfirstlane(es.y);
    edge_update(e, gath(s));
  };

  int j = j0;
  if ((j & 1) && j < j1) { edge_single(j); ++j; }   // peel to 16B alignment
  for (; j + 1 < j1; j += 2) {
    int4 q = *(const int4*)(csr2 + j);  // two (edge,src) pairs, one dwordx4
    int e0 = __builtin_amdgcn_readfirstlane(q.x);
    int s0 = __builtin_amdgcn_readfirstlane(q.y);
    int e1 = __builtin_amdgcn_readfirstlane(q.z);
    int s1 = __builtin_amdgcn_readfirstlane(q.w);
    f32x2 xls0 = gath(s0);
    f32x2 xls1 = gath(s1);
    edge_update(e0, xls0);
    edge_update(e1, xls1);
  }
  if (j < j1) edge_single(j);

  // ---- self-loop ----
  int dg = j1 - j0;
  f32x2 ee = (dg > 0) ? (eesum * (1.f / (float)dg) - xr2) : (f32x2)0.f;
  f32x2 mm = xl2 + xr2 + ee;
  f32x2 tt = __builtin_elementwise_fma(
      av08, __builtin_elementwise_max(mm, (f32x2)0.f), av02 * mm);
  float p = head8_sum(tt.x + tt.y);
  if (p > m) {
    float sc = exp2f(m - p);
    acc = acc * sc + xl2;
    den = fmaf(den, sc, 1.f);
  } else {
    float w = exp2f(p - m);
    acc = __builtin_elementwise_fma((f32x2)w, xl2, acc);
    den += w;
  }

  f32x2 b2 = *(const f32x2*)(bias + c0);
  f32x2 x2 = *(const f32x2*)(x + n * HC + c0);
  f32x2 o = acc * (1.f / den) + b2 + x2;
  *(f32x2*)(out + n * HC + c0) = o;
}

// ---------- K6: GraphNorm segment sums (grid-parallel over group slices) ----------
#define GN_SLICES 32
__global__ void __launch_bounds__(128) gn_stats(
    const float* __restrict__ out, const int* __restrict__ gstart,
    float* __restrict__ gsum, float* __restrict__ gsq) {
  int g = blockIdx.x >> 5;
  int slice = blockIdx.x & 31;
  int s0 = gstart[g], s1 = gstart[g + 1];
  int cnt = s1 - s0;
  if (cnt <= 0) return;
  int chunk = (cnt + GN_SLICES - 1) / GN_SLICES;
  int lo = s0 + slice * chunk;
  int hi = lo + chunk; if (hi > s1) hi = s1;
  if (lo >= hi) return;
  int ch = threadIdx.x;
  float sum = 0.f, sq = 0.f;
  for (int nrow = lo; nrow < hi; ++nrow) {
    float v = out[(long)nrow * HC + ch];
    sum += v; sq += v * v;
  }
  atomicAdd(&gsum[g * HC + ch], sum);
  atomicAdd(&gsq[g * HC + ch], sq);
}

// ---------- K7: normalize + affine + ELU, with inline mean/istd (fused finalize) ----
__global__ void gn_apply(float* __restrict__ out, const int* __restrict__ batch,
                         const float* __restrict__ gsum, const float* __restrict__ gsq,
                         const int* __restrict__ gstart, const float* __restrict__ gms,
                         const float* __restrict__ gnw, const float* __restrict__ gnb, int N) {
  long i = (long)blockIdx.x * 256 + threadIdx.x;     // float4 index
  if (i >= (long)N * 32) return;
  int c4 = (int)(i & 31);
  long n = i >> 5;
  int g = batch[n];
  float cnt = (float)(gstart[g + 1] - gstart[g]);
  if (cnt < 1.f) cnt = 1.f;
  float ic = 1.f / cnt;
  float4 su = ((const float4*)gsum)[g * 32 + c4];
  float4 sq = ((const float4*)gsq)[g * 32 + c4];
  float4 ms4 = ((const float4*)gms)[c4];
  float4 v = ((const float4*)out)[i];
  float4 w  = ((const float4*)gnw)[c4];
  float4 b  = ((const float4*)gnb)[c4];
  float4 o;
  #pragma unroll
  for (int k = 0; k < 4; ++k) {
    float mean = (&su.x)[k] * ic;
    float c = (&ms4.x)[k] * mean;                       // subtracted constant
    float var = (&sq.x)[k] * ic - 2.f * c * mean + c * c;
    float istd = rsqrtf(var + GEPS);
    float oo = fmaf((&w.x)[k] * ((&v.x)[k] - c), istd, (&b.x)[k]);
    (&o.x)[k] = oo > 0.f ? oo : expm1f(oo);
  }
  ((float4*)out)[i] = o;
}

extern "C" void kernel_launch(void* const* d_in, const int* in_sizes, int n_in,
                              void* d_out, int out_size, void* d_ws, size_t ws_size,
                              hipStream_t stream) {
  const float* x    = (const float*)d_in[0];
  const int*   ei   = (const int*)d_in[1];
  const float* ea   = (const float*)d_in[2];
  const int*   batch= (const int*)d_in[3];
  const float* Wl   = (const float*)d_in[4];
  const float* bl   = (const float*)d_in[5];
  const float* Wr   = (const float*)d_in[6];
  const float* br   = (const float*)d_in[7];
  const float* We   = (const float*)d_in[8];
  const float* att  = (const float*)d_in[9];
  const float* bias = (const float*)d_in[10];
  const float* gnw  = (const float*)d_in[11];
  const float* gnb  = (const float*)d_in[12];
  const float* gms  = (const float*)d_in[13];
  int N = in_sizes[0] / HC;
  int E = in_sizes[2] / EDIM;
  float* out = (float*)d_out;
  (void)n_in; (void)out_size; (void)ws_size;

  // ---- workspace carve-up (4-byte words, 16B aligned blocks) ----
  float* wsf = (float*)d_ws;
  size_t off = 0;
  auto alloc = [&](size_t words) -> float* {
    float* p = wsf + off;
    off += (words + 3) & ~(size_t)3;
    return p;
  };
  int*      deg     = (int*)alloc(N);
  float*    gsum    = alloc(NG * HC);
  float*    gsq     = alloc(NG * HC);
  int*      genc    = (int*)alloc(NG);
  size_t zero_words = off;                 // everything above starts at 0
  int*      gstart  = (int*)alloc(NG + 1);
  int*      bsum    = (int*)alloc(256);
  int*      bofs    = (int*)alloc(256);
  int*      offsets = (int*)alloc((size_t)N + 1);
  float*    xl      = alloc((size_t)N * HC);
  float*    xr      = alloc((size_t)N * HC);
  unsigned* xlh     = (unsigned*)alloc((size_t)N * (HC / 2));
  int2*     csr2    = (int2*)alloc((size_t)E * 2 + 8);

  int nb = (N + 255) / 256;   // scan blocks (<=256 by construction for N<=65536)

  zero_k<<<(unsigned)((zero_words + 255) / 256), 256, 0, stream>>>(wsf, zero_words);
  count_deg_mark<<<(E + 255) / 256, 256, 0, stream>>>(ei, deg, batch, genc, E, N);
  gemm_tiled<<<(N + GEMM_ROWS - 1) / GEMM_ROWS, 256, 0, stream>>>(x, Wl, bl, Wr, br, xl, xr, xlh, N);
  scan1<<<nb, 256, 0, stream>>>(deg, bsum, N);
  scan2<<<1, 256, 0, stream>>>(bsum, bofs, nb, offsets, N, genc, gstart);
  scan3<<<nb, 256, 0, stream>>>(deg, bofs, offsets, N);
  fill_csr<<<(E + 255) / 256, 256, 0, stream>>>(ei, deg, offsets, csr2, E);
  fused_node<<<N, 64, 0, stream>>>(offsets, csr2, ea, xlh, xl, xr, We, att, x, bias, out, N);
  gn_stats<<<NG * GN_SLICES, 128, 0, stream>>>(out, gstart, gsum, gsq);
  {
    long tot = (long)N * 32;
    gn_apply<<<(unsigned)((tot + 255) / 256), 256, 0, stream>>>(out, batch, gsum, gsq, gstart, gms, gnw, gnb, N);
  }
}